// Round 19
// baseline (102.049 us; speedup 1.0000x reference)
//
#include <hip/hip_runtime.h>
#include <math.h>

// DynamicRouting: C=1024, K=64, H=512.
// Round-19: r18 ablation verdict: proj = 87us of the 100, route = ~10us and
// streams at 6.4 TB/s -> proj's 1.6 TB/s is DUTY CYCLE (memory idle during
// MFMA/epilogue, 1 block/CU). Fix: K-split proj (2048 blocks x 32 k-rows),
// regs slimmed for 2 blocks/CU co-residency (staging of one overlaps compute
// of the other) + LDS-transpose epilogue (4 coalesced half8 stores vs 64
// scattered 2B stores). Route kernel unchanged (r18-verified).
// Verified geometry (r12-r18): slab swizzle, Wp B-frag order, MFMA layout
// acc[i*4+j][r] = xh[k][g], k = i*16+(lane>>4)*4+r (+kh*32), g = wave*64+j*16+(lane&15).

#define KC 64
#define HD 512

typedef _Float16 half8  __attribute__((ext_vector_type(8)));
typedef _Float16 half4v __attribute__((ext_vector_type(4)));
typedef float    f32x4  __attribute__((ext_vector_type(4)));

// ---- W (fp32 [g][h]) -> fp16 in B-fragment order (verified r12) ----
__launch_bounds__(256)
__global__ void cast_w_kernel(const float* __restrict__ W, _Float16* __restrict__ Wp) {
    int u    = blockIdx.x * 256 + threadIdx.x;    // 0..32767
    int lane = u & 63;
    int j    = (u >> 6) & 3;
    int ks   = (u >> 8) & 1;
    int hs   = (u >> 9) & 7;
    int wv   = (u >> 12) & 7;
    int g  = wv * 64 + j * 16 + (lane & 15);
    int h0 = hs * 64 + ks * 32 + (lane >> 4) * 8;
    const float4* src = reinterpret_cast<const float4*>(W + (size_t)g * HD + h0);
    float4 a = src[0], b = src[1];
    half8 h = { (_Float16)a.x, (_Float16)a.y, (_Float16)a.z, (_Float16)a.w,
                (_Float16)b.x, (_Float16)b.y, (_Float16)b.z, (_Float16)b.w };
    *reinterpret_cast<half8*>(Wp + (size_t)u * 8) = h;
}

// ---- kernel A: half-capsule projection. block b: c = b>>1, k-rows kh*32..+31 ----
__launch_bounds__(512, 4)   // cap 128 regs -> 2 blocks/CU co-resident
__global__ void proj_kernel(const float* __restrict__ enc,
                            const _Float16* __restrict__ Wp,
                            _Float16* __restrict__ xhat) {
    __shared__ _Float16 slab[8][4][64][8];      // 32 KB; aliased [32][512] in epilogue

    const int tid  = threadIdx.x;
    const int lane = tid & 63;
    const int wave = tid >> 6;                  // 0..7 (g-slice)
    const int l15  = lane & 15, l4 = lane >> 4;
    const int c    = blockIdx.x >> 1;
    const int kh   = blockIdx.x & 1;
    const float* ebase = enc + ((size_t)c * KC + kh * 32) * HD;
    const _Float16* wbase = Wp + ((size_t)wave << 15) + (lane << 3);

    // staging geometry (verified r12, 32-row variant)
    const int r0   = tid >> 4;                  // 0..31
    const int c40  = (tid & 15) << 2;           // 0..60
    const int ks_w = c40 >> 5;
    const int l4g  = (c40 >> 3) & 3;
    const int e0w  = c40 & 7;                   // 0 or 4
    const int prow = (l4g * 16 + (r0 & 15)) ^ (l4g << 1);
    const int p0   = (r0 >> 4) * 2 + ks_w;      // 0..3
    const int plane_r = lane ^ ((lane >> 4) << 1);

    // ---- stage 32x512 fp32 -> fp16, two 4-deep batches (reg-lean) ----
    {
        float4 e0 = *reinterpret_cast<const float4*>(ebase + (size_t)r0 * HD + 0 * 64 + c40);
        float4 e1 = *reinterpret_cast<const float4*>(ebase + (size_t)r0 * HD + 1 * 64 + c40);
        float4 e2 = *reinterpret_cast<const float4*>(ebase + (size_t)r0 * HD + 2 * 64 + c40);
        float4 e3 = *reinterpret_cast<const float4*>(ebase + (size_t)r0 * HD + 3 * 64 + c40);
        half4v h0 = { (_Float16)e0.x, (_Float16)e0.y, (_Float16)e0.z, (_Float16)e0.w };
        half4v h1 = { (_Float16)e1.x, (_Float16)e1.y, (_Float16)e1.z, (_Float16)e1.w };
        half4v h2 = { (_Float16)e2.x, (_Float16)e2.y, (_Float16)e2.z, (_Float16)e2.w };
        half4v h3 = { (_Float16)e3.x, (_Float16)e3.y, (_Float16)e3.z, (_Float16)e3.w };
        *reinterpret_cast<half4v*>(&slab[0][p0][prow][e0w]) = h0;
        *reinterpret_cast<half4v*>(&slab[1][p0][prow][e0w]) = h1;
        *reinterpret_cast<half4v*>(&slab[2][p0][prow][e0w]) = h2;
        *reinterpret_cast<half4v*>(&slab[3][p0][prow][e0w]) = h3;
    }
    {
        float4 e0 = *reinterpret_cast<const float4*>(ebase + (size_t)r0 * HD + 4 * 64 + c40);
        float4 e1 = *reinterpret_cast<const float4*>(ebase + (size_t)r0 * HD + 5 * 64 + c40);
        float4 e2 = *reinterpret_cast<const float4*>(ebase + (size_t)r0 * HD + 6 * 64 + c40);
        float4 e3 = *reinterpret_cast<const float4*>(ebase + (size_t)r0 * HD + 7 * 64 + c40);
        half4v h0 = { (_Float16)e0.x, (_Float16)e0.y, (_Float16)e0.z, (_Float16)e0.w };
        half4v h1 = { (_Float16)e1.x, (_Float16)e1.y, (_Float16)e1.z, (_Float16)e1.w };
        half4v h2 = { (_Float16)e2.x, (_Float16)e2.y, (_Float16)e2.z, (_Float16)e2.w };
        half4v h3 = { (_Float16)e3.x, (_Float16)e3.y, (_Float16)e3.z, (_Float16)e3.w };
        *reinterpret_cast<half4v*>(&slab[4][p0][prow][e0w]) = h0;
        *reinterpret_cast<half4v*>(&slab[5][p0][prow][e0w]) = h1;
        *reinterpret_cast<half4v*>(&slab[6][p0][prow][e0w]) = h2;
        *reinterpret_cast<half4v*>(&slab[7][p0][prow][e0w]) = h3;
    }

    f32x4 acc[8];
    #pragma unroll
    for (int i = 0; i < 8; ++i) acc[i] = (f32x4){0.f, 0.f, 0.f, 0.f};

    __syncthreads();

    // ---- 8 barrier-free MFMA phases (bf single-buffer, per-hs load) ----
    half8 bf[8];
    #pragma unroll
    for (int hs = 0; hs < 8; ++hs) {
        #pragma unroll
        for (int q = 0; q < 8; ++q)
            bf[q] = *reinterpret_cast<const half8*>(wbase + hs * 4096 + q * 512);
        #pragma unroll
        for (int ks = 0; ks < 2; ++ks) {
            half8 af[2];
            #pragma unroll
            for (int i = 0; i < 2; ++i)
                af[i] = *reinterpret_cast<const half8*>(&slab[hs][i * 2 + ks][plane_r][0]);
            #pragma unroll
            for (int i = 0; i < 2; ++i)
                #pragma unroll
                for (int j = 0; j < 4; ++j)
                    acc[i * 4 + j] = __builtin_amdgcn_mfma_f32_16x16x32_f16(
                        af[i], bf[ks * 4 + j], acc[i * 4 + j], 0, 0, 0);
        }
    }

    // ---- epilogue: acc -> LDS (transpose) -> coalesced global half8 stores ----
    __syncthreads();                            // all slab MFMA reads done (WAR)
    _Float16 (*xo)[HD] = reinterpret_cast<_Float16 (*)[HD]>(&slab[0][0][0][0]);  // [32][512]
    #pragma unroll
    for (int i = 0; i < 2; ++i) {
        #pragma unroll
        for (int j = 0; j < 4; ++j) {
            f32x4 v = acc[i * 4 + j];
            const int g  = wave * 64 + j * 16 + l15;
            const int kb = i * 16 + l4 * 4;
            #pragma unroll
            for (int r = 0; r < 4; ++r) xo[kb + r][g] = (_Float16)v[r];
        }
    }
    __syncthreads();
    {
        _Float16* xrow = xhat + ((size_t)c * KC + kh * 32) * HD;
        #pragma unroll
        for (int q = 0; q < 4; ++q) {
            int flat = tid + q * 512;           // 0..2047 half8 chunks
            int row  = flat >> 6;               // 64 chunks per row
            int col  = (flat & 63) << 3;
            half8 v = *reinterpret_cast<const half8*>(&xo[row][col]);
            *reinterpret_cast<half8*>(xrow + (size_t)row * HD + col) = v;
        }
    }
}

// ---- kernel B: routing from xhat (r18-verified) ----
__launch_bounds__(512, 2)
__global__ void route_kernel(const _Float16* __restrict__ xhat,
                             float* __restrict__ out) {
    __shared__ _Float16 xh[KC][520];            // ~66.5 KB (pad 520)
    __shared__ float chatL[HD];
    __shared__ float dL[KC];
    __shared__ float bdotL[KC];
    __shared__ float red[8];

    const int tid  = threadIdx.x;
    const int lane = tid & 63;
    const int wave = tid >> 6;
    const int c    = blockIdx.x;
    const _Float16* xsrc = xhat + (size_t)c * (KC * HD);

    #pragma unroll
    for (int q = 0; q < 8; ++q) {
        int flat = tid + q * 512;               // 0..4095
        int row  = flat >> 6;
        int col  = (flat & 63) << 3;
        half8 v = *reinterpret_cast<const half8*>(xsrc + (size_t)row * HD + col);
        *reinterpret_cast<half8*>(&xh[row][col]) = v;
    }
    __syncthreads();

    float breg = 0.0f;
    float alpha = 0.0f;

    #pragma unroll
    for (int it = 0; it < 3; ++it) {
        if (it > 0) {
            breg += bdotL[lane];
            float m = breg;
            #pragma unroll
            for (int off = 32; off; off >>= 1) m = fmaxf(m, __shfl_xor(m, off));
            float e = expf(breg - m);
            float se = e;
            #pragma unroll
            for (int off = 32; off; off >>= 1) se += __shfl_xor(se, off);
            if (wave == 0) dL[lane] = e / se;
            __syncthreads();
        }

        {
            float cs = 0.f;
            if (it == 0) {
                #pragma unroll 8
                for (int k = 0; k < KC; ++k) cs += (float)xh[k][tid];
                cs *= (1.0f / 64.0f);
            } else {
                #pragma unroll 8
                for (int k = 0; k < KC; ++k) cs += dL[k] * (float)xh[k][tid];
            }
            chatL[tid] = cs;
            float p = cs * cs;
            #pragma unroll
            for (int off = 32; off; off >>= 1) p += __shfl_xor(p, off);
            if (lane == 0) red[wave] = p;
        }
        __syncthreads();
        {
            float n2 = red[0] + red[1] + red[2] + red[3]
                     + red[4] + red[5] + red[6] + red[7];
            alpha = sqrtf(n2) / (1.0f + n2);
        }

        if (it < 2) {
            float4 cA = *reinterpret_cast<const float4*>(&chatL[lane * 8]);
            float4 cB = *reinterpret_cast<const float4*>(&chatL[lane * 8 + 4]);
            #pragma unroll
            for (int kk = 0; kk < 8; ++kk) {
                int k = wave * 8 + kk;
                half8 x = *reinterpret_cast<const half8*>(&xh[k][lane * 8]);
                float p = (float)x[0] * cA.x + (float)x[1] * cA.y
                        + (float)x[2] * cA.z + (float)x[3] * cA.w
                        + (float)x[4] * cB.x + (float)x[5] * cB.y
                        + (float)x[6] * cB.z + (float)x[7] * cB.w;
                #pragma unroll
                for (int off = 32; off; off >>= 1) p += __shfl_xor(p, off);
                if (lane == 0) bdotL[k] = alpha * p;
            }
            __syncthreads();
        } else {
            out[(size_t)c * HD + tid] = alpha * chatL[tid];
        }
    }
}

// ---- fallback: r16 fused kernel (verified) ----
__launch_bounds__(512, 2)
__global__ void fused_kernel(const float* __restrict__ enc,
                             const _Float16* __restrict__ Wp,
                             float* __restrict__ out) {
    __shared__ _Float16 slab[8][8][64][8];
    __shared__ float chatL[HD];
    __shared__ float bpart[2][8][KC];
    __shared__ float redp[2][8];

    const int tid  = threadIdx.x;
    const int lane = tid & 63;
    const int wave = tid >> 6;
    const int l15  = lane & 15, l4 = lane >> 4;
    const int c    = blockIdx.x;
    const float* ebase = enc + (size_t)c * (KC * HD);
    const _Float16* wbase = Wp + ((size_t)wave << 15) + (lane << 3);

    const int r0   = tid >> 4;
    const int c40  = (tid & 15) << 2;
    const int ks_w = c40 >> 5;
    const int l4g  = (c40 >> 3) & 3;
    const int e0w  = c40 & 7;
    const int prow = (l4g * 16 + (r0 & 15)) ^ (l4g << 1);
    const int p0   = (r0 >> 4) * 2 + ks_w;
    const int p1   = p0 + 4;
    const int plane_r = lane ^ ((lane >> 4) << 1);

    half8 bf[2][8];
    auto bload = [&](int hs) {
        #pragma unroll
        for (int q = 0; q < 8; ++q)
            bf[hs & 1][q] = *reinterpret_cast<const half8*>(wbase + hs * 4096 + q * 512);
    };

    float4 ev[8][2];
    #pragma unroll
    for (int hs = 0; hs < 8; ++hs) {
        ev[hs][0] = *reinterpret_cast<const float4*>(ebase + (size_t)r0 * HD + hs * 64 + c40);
        ev[hs][1] = *reinterpret_cast<const float4*>(ebase + (size_t)(r0 + 32) * HD + hs * 64 + c40);
    }
    bload(0);
    #pragma unroll
    for (int hs = 0; hs < 8; ++hs) {
        float4 v0 = ev[hs][0], v1 = ev[hs][1];
        half4v h0 = { (_Float16)v0.x, (_Float16)v0.y, (_Float16)v0.z, (_Float16)v0.w };
        half4v h1 = { (_Float16)v1.x, (_Float16)v1.y, (_Float16)v1.z, (_Float16)v1.w };
        *reinterpret_cast<half4v*>(&slab[hs][p0][prow][e0w]) = h0;
        *reinterpret_cast<half4v*>(&slab[hs][p1][prow][e0w]) = h1;
    }

    f32x4 acc[16];
    #pragma unroll
    for (int i = 0; i < 16; ++i) acc[i] = (f32x4){0.f, 0.f, 0.f, 0.f};

    __syncthreads();

    #pragma unroll
    for (int hs = 0; hs < 8; ++hs) {
        if (hs < 7) bload(hs + 1);
        #pragma unroll
        for (int ks = 0; ks < 2; ++ks) {
            half8 af[4];
            #pragma unroll
            for (int i = 0; i < 4; ++i)
                af[i] = *reinterpret_cast<const half8*>(&slab[hs][i * 2 + ks][plane_r][0]);
            #pragma unroll
            for (int i = 0; i < 4; ++i)
                #pragma unroll
                for (int j = 0; j < 4; ++j)
                    acc[i * 4 + j] = __builtin_amdgcn_mfma_f32_16x16x32_f16(
                        af[i], bf[hs & 1][ks * 4 + j], acc[i * 4 + j], 0, 0, 0);
        }
    }

    float breg = 0.0f;
    float chv[4];
    {
        #pragma unroll
        for (int j = 0; j < 4; ++j) chv[j] = 0.f;
        #pragma unroll
        for (int i = 0; i < 4; ++i)
            #pragma unroll
            for (int r = 0; r < 4; ++r) {
                #pragma unroll
                for (int j = 0; j < 4; ++j)
                    chv[j] += (1.0f / 64.0f) * acc[i * 4 + j][r];
            }
        #pragma unroll
        for (int j = 0; j < 4; ++j) {
            chv[j] += __shfl_xor(chv[j], 16);
            chv[j] += __shfl_xor(chv[j], 32);
        }
        float p = chv[0] * chv[0] + chv[1] * chv[1] + chv[2] * chv[2] + chv[3] * chv[3];
        #pragma unroll
        for (int off = 1; off <= 8; off <<= 1) p += __shfl_xor(p, off);
        if (lane == 0) redp[0][wave] = p;
        #pragma unroll
        for (int i = 0; i < 4; ++i)
            #pragma unroll
            for (int r = 0; r < 4; ++r) {
                float s = acc[i * 4 + 0][r] * chv[0] + acc[i * 4 + 1][r] * chv[1]
                        + acc[i * 4 + 2][r] * chv[2] + acc[i * 4 + 3][r] * chv[3];
                #pragma unroll
                for (int off = 1; off <= 8; off <<= 1) s += __shfl_xor(s, off);
                if (l15 == 0) bpart[0][wave][i * 16 + l4 * 4 + r] = s;
            }
        __syncthreads();
    }
    #pragma unroll
    for (int it = 1; it < 3; ++it) {
        const int rp = (it - 1) & 1, wp = it & 1;
        float n2 = 0.f;
        #pragma unroll
        for (int w = 0; w < 8; ++w) n2 += redp[rp][w];
        float alpha = sqrtf(n2) / (1.0f + n2);
        float dot = 0.f;
        #pragma unroll
        for (int w = 0; w < 8; ++w) dot += bpart[rp][w][lane];
        breg += alpha * dot;
        float m = breg;
        #pragma unroll
        for (int off = 32; off; off >>= 1) m = fmaxf(m, __shfl_xor(m, off));
        float e = expf(breg - m);
        float se = e;
        #pragma unroll
        for (int off = 32; off; off >>= 1) se += __shfl_xor(se, off);
        float dl = e / se;
        #pragma unroll
        for (int j = 0; j < 4; ++j) chv[j] = 0.f;
        #pragma unroll
        for (int i = 0; i < 4; ++i)
            #pragma unroll
            for (int r = 0; r < 4; ++r) {
                float dk = __shfl(dl, i * 16 + l4 * 4 + r);
                #pragma unroll
                for (int j = 0; j < 4; ++j)
                    chv[j] += dk * acc[i * 4 + j][r];
            }
        #pragma unroll
        for (int j = 0; j < 4; ++j) {
            chv[j] += __shfl_xor(chv[j], 16);
            chv[j] += __shfl_xor(chv[j], 32);
        }
        float p = chv[0] * chv[0] + chv[1] * chv[1] + chv[2] * chv[2] + chv[3] * chv[3];
        #pragma unroll
        for (int off = 1; off <= 8; off <<= 1) p += __shfl_xor(p, off);
        if (lane == 0) redp[wp][wave] = p;

        if (it < 2) {
            #pragma unroll
            for (int i = 0; i < 4; ++i)
                #pragma unroll
                for (int r = 0; r < 4; ++r) {
                    float s = acc[i * 4 + 0][r] * chv[0] + acc[i * 4 + 1][r] * chv[1]
                            + acc[i * 4 + 2][r] * chv[2] + acc[i * 4 + 3][r] * chv[3];
                    #pragma unroll
                    for (int off = 1; off <= 8; off <<= 1) s += __shfl_xor(s, off);
                    if (l15 == 0) bpart[wp][wave][i * 16 + l4 * 4 + r] = s;
                }
            __syncthreads();
        } else {
            if (l4 == 0) {
                #pragma unroll
                for (int j = 0; j < 4; ++j)
                    chatL[wave * 64 + j * 16 + l15] = chv[j];
            }
            __syncthreads();
            float n2f = 0.f;
            #pragma unroll
            for (int w = 0; w < 8; ++w) n2f += redp[wp][w];
            float alphaf = sqrtf(n2f) / (1.0f + n2f);
            out[(size_t)c * HD + tid] = alphaf * chatL[tid];
        }
    }
}

extern "C" void kernel_launch(void* const* d_in, const int* in_sizes, int n_in,
                              void* d_out, int out_size, void* d_ws, size_t ws_size,
                              hipStream_t stream) {
    const float* enc = (const float*)d_in[0];   // [1024, 64, 512] fp32
    const float* W   = (const float*)d_in[1];   // [512, 512] fp32
    float* out       = (float*)d_out;           // [1024, 512] fp32
    _Float16* Wp     = (_Float16*)d_ws;         // 512 KB, B-fragment order
    (void)in_sizes; (void)n_in; (void)out_size;

    const size_t wp_bytes   = (size_t)512 * 1024;
    const size_t xhat_bytes = (size_t)1024 * KC * HD * sizeof(_Float16);  // 64 MB

    cast_w_kernel<<<128, 256, 0, stream>>>(W, Wp);
    if (ws_size >= wp_bytes + xhat_bytes) {
        _Float16* xhat = (_Float16*)((char*)d_ws + wp_bytes);
        proj_kernel<<<2048, 512, 0, stream>>>(enc, Wp, xhat);
        route_kernel<<<1024, 512, 0, stream>>>(xhat, out);
    } else {
        fused_kernel<<<1024, 512, 0, stream>>>(enc, Wp, out);
    }
}

// Round 20
// 82.260 us; speedup vs baseline: 1.2406x; 1.2406x over previous
//
#include <hip/hip_runtime.h>
#include <math.h>

// DynamicRouting: C=1024, K=64, H=512.
// Round-20: CPB=2 fused with bf SHARED across capsules.
// Falsified levers (r11-r19): barriers, prefetch depth, occupancy, block
// count, co-residency -- floor pinned at ~81-90us = per-CU rounds x chain.
// Untested axis: work per Wp stream. Here: for hs { bf once; 2 caps MFMA }
// -> per-CU rounds 4->2, Wp traffic 512->256 MB, MFMA per bf-stall x2.
// Both slabs (128 KB) staged in one burst; in-reg routing (r16-verified)
// cap-unrolled with shared barriers. Geometry verified r12-r19:
//   acc[cap][i*4+j][r] = xh[k][g], k=i*16+(lane>>4)*4+r, g=wave*64+j*16+(lane&15).

#define KC 64
#define HD 512
#define NT 512
#define CPB 2

typedef _Float16 half8  __attribute__((ext_vector_type(8)));
typedef _Float16 half4v __attribute__((ext_vector_type(4)));
typedef float    f32x4  __attribute__((ext_vector_type(4)));

// ---- W (fp32 [g][h]) -> fp16 in B-fragment order (verified r12) ----
__launch_bounds__(256)
__global__ void cast_w_kernel(const float* __restrict__ W, _Float16* __restrict__ Wp) {
    int u    = blockIdx.x * 256 + threadIdx.x;    // 0..32767
    int lane = u & 63;
    int j    = (u >> 6) & 3;
    int ks   = (u >> 8) & 1;
    int hs   = (u >> 9) & 7;
    int wv   = (u >> 12) & 7;
    int g  = wv * 64 + j * 16 + (lane & 15);
    int h0 = hs * 64 + ks * 32 + (lane >> 4) * 8;
    const float4* src = reinterpret_cast<const float4*>(W + (size_t)g * HD + h0);
    float4 a = src[0], b = src[1];
    half8 h = { (_Float16)a.x, (_Float16)a.y, (_Float16)a.z, (_Float16)a.w,
                (_Float16)b.x, (_Float16)b.y, (_Float16)b.z, (_Float16)b.w };
    *reinterpret_cast<half8*>(Wp + (size_t)u * 8) = h;
}

// ---- fused: 2 capsules per block, bf shared, in-reg routing ----
__launch_bounds__(NT, 2)   // cap 256 VGPR (est ~210 live; r13 lesson: watch WRITE_SIZE)
__global__ void routing_kernel(const float* __restrict__ enc,
                               const _Float16* __restrict__ Wp,
                               float* __restrict__ out) {
    __shared__ _Float16 slab[CPB][8][8][64][8];   // 128 KB [cap][hs][plane][row][e]
    __shared__ float chatL[CPB][HD];              // 4 KB
    __shared__ float bpart[CPB][2][8][KC];        // 8 KB
    __shared__ float redp[CPB][2][8];             // 256 B

    const int tid  = threadIdx.x;
    const int lane = tid & 63;
    const int wave = tid >> 6;
    const int l15  = lane & 15, l4 = lane >> 4;
    const int c0   = blockIdx.x * CPB;
    const _Float16* wbase = Wp + ((size_t)wave << 15) + (lane << 3);

    // staging geometry (verified r12)
    const int r0   = tid >> 4;                  // 0..31
    const int c40  = (tid & 15) << 2;           // 0..60
    const int ks_w = c40 >> 5;
    const int l4g  = (c40 >> 3) & 3;
    const int e0w  = c40 & 7;                   // 0 or 4
    const int prow = (l4g * 16 + (r0 & 15)) ^ (l4g << 1);
    const int p0   = (r0 >> 4) * 2 + ks_w;
    const int p1   = p0 + 4;
    const int plane_r = lane ^ ((lane >> 4) << 1);

    // ---- stage BOTH capsules (two 16-load bursts, regs transient) ----
    #pragma unroll
    for (int cap = 0; cap < CPB; ++cap) {
        const float* eb = enc + (size_t)(c0 + cap) * (KC * HD);
        float4 ev[8][2];
        #pragma unroll
        for (int hs = 0; hs < 8; ++hs) {
            ev[hs][0] = *reinterpret_cast<const float4*>(eb + (size_t)r0 * HD + hs * 64 + c40);
            ev[hs][1] = *reinterpret_cast<const float4*>(eb + (size_t)(r0 + 32) * HD + hs * 64 + c40);
        }
        #pragma unroll
        for (int hs = 0; hs < 8; ++hs) {
            float4 v0 = ev[hs][0], v1 = ev[hs][1];
            half4v h0 = { (_Float16)v0.x, (_Float16)v0.y, (_Float16)v0.z, (_Float16)v0.w };
            half4v h1 = { (_Float16)v1.x, (_Float16)v1.y, (_Float16)v1.z, (_Float16)v1.w };
            *reinterpret_cast<half4v*>(&slab[cap][hs][p0][prow][e0w]) = h0;
            *reinterpret_cast<half4v*>(&slab[cap][hs][p1][prow][e0w]) = h1;
        }
    }

    f32x4 acc[CPB][16];
    #pragma unroll
    for (int cap = 0; cap < CPB; ++cap)
        #pragma unroll
        for (int i = 0; i < 16; ++i) acc[cap][i] = (f32x4){0.f, 0.f, 0.f, 0.f};

    __syncthreads();                            // the only projection barrier

    // ---- projection: 8 phases; bf loaded ONCE per hs, used by both caps ----
    #pragma unroll
    for (int hs = 0; hs < 8; ++hs) {
        half8 bf[8];
        #pragma unroll
        for (int q = 0; q < 8; ++q)
            bf[q] = *reinterpret_cast<const half8*>(wbase + hs * 4096 + q * 512);
        #pragma unroll
        for (int ks = 0; ks < 2; ++ks) {
            #pragma unroll
            for (int cap = 0; cap < CPB; ++cap) {
                half8 af[4];
                #pragma unroll
                for (int i = 0; i < 4; ++i)
                    af[i] = *reinterpret_cast<const half8*>(&slab[cap][hs][i * 2 + ks][plane_r][0]);
                #pragma unroll
                for (int i = 0; i < 4; ++i)
                    #pragma unroll
                    for (int j = 0; j < 4; ++j)
                        acc[cap][i * 4 + j] = __builtin_amdgcn_mfma_f32_16x16x32_f16(
                            af[i], bf[ks * 4 + j], acc[cap][i * 4 + j], 0, 0, 0);
            }
        }
    }

    // ---- routing: r16-verified, cap-unrolled, shared barriers ----
    float brg[CPB] = {0.f, 0.f};
    float chv[CPB][4];

    // iter 0: dk = 1/64
    #pragma unroll
    for (int cap = 0; cap < CPB; ++cap) {
        #pragma unroll
        for (int j = 0; j < 4; ++j) chv[cap][j] = 0.f;
        #pragma unroll
        for (int i = 0; i < 4; ++i)
            #pragma unroll
            for (int r = 0; r < 4; ++r) {
                #pragma unroll
                for (int j = 0; j < 4; ++j)
                    chv[cap][j] += (1.0f / 64.0f) * acc[cap][i * 4 + j][r];
            }
        #pragma unroll
        for (int j = 0; j < 4; ++j) {
            chv[cap][j] += __shfl_xor(chv[cap][j], 16);
            chv[cap][j] += __shfl_xor(chv[cap][j], 32);
        }
        float p = chv[cap][0] * chv[cap][0] + chv[cap][1] * chv[cap][1]
                + chv[cap][2] * chv[cap][2] + chv[cap][3] * chv[cap][3];
        #pragma unroll
        for (int off = 1; off <= 8; off <<= 1) p += __shfl_xor(p, off);
        if (lane == 0) redp[cap][0][wave] = p;
        #pragma unroll
        for (int i = 0; i < 4; ++i)
            #pragma unroll
            for (int r = 0; r < 4; ++r) {
                float s = acc[cap][i * 4 + 0][r] * chv[cap][0] + acc[cap][i * 4 + 1][r] * chv[cap][1]
                        + acc[cap][i * 4 + 2][r] * chv[cap][2] + acc[cap][i * 4 + 3][r] * chv[cap][3];
                #pragma unroll
                for (int off = 1; off <= 8; off <<= 1) s += __shfl_xor(s, off);
                if (l15 == 0) bpart[cap][0][wave][i * 16 + l4 * 4 + r] = s;
            }
    }
    __syncthreads();

    // iters 1,2
    #pragma unroll
    for (int it = 1; it < 3; ++it) {
        const int rp = (it - 1) & 1, wp = it & 1;
        #pragma unroll
        for (int cap = 0; cap < CPB; ++cap) {
            float n2 = 0.f;
            #pragma unroll
            for (int w = 0; w < 8; ++w) n2 += redp[cap][rp][w];
            float alpha = sqrtf(n2) / (1.0f + n2);
            float dot = 0.f;
            #pragma unroll
            for (int w = 0; w < 8; ++w) dot += bpart[cap][rp][w][lane];
            brg[cap] += alpha * dot;
            float m = brg[cap];
            #pragma unroll
            for (int off = 32; off; off >>= 1) m = fmaxf(m, __shfl_xor(m, off));
            float e = expf(brg[cap] - m);
            float se = e;
            #pragma unroll
            for (int off = 32; off; off >>= 1) se += __shfl_xor(se, off);
            float dl = e / se;                  // d[k=lane]
            #pragma unroll
            for (int j = 0; j < 4; ++j) chv[cap][j] = 0.f;
            #pragma unroll
            for (int i = 0; i < 4; ++i)
                #pragma unroll
                for (int r = 0; r < 4; ++r) {
                    float dk = __shfl(dl, i * 16 + l4 * 4 + r);
                    #pragma unroll
                    for (int j = 0; j < 4; ++j)
                        chv[cap][j] += dk * acc[cap][i * 4 + j][r];
                }
            #pragma unroll
            for (int j = 0; j < 4; ++j) {
                chv[cap][j] += __shfl_xor(chv[cap][j], 16);
                chv[cap][j] += __shfl_xor(chv[cap][j], 32);
            }
            float p = chv[cap][0] * chv[cap][0] + chv[cap][1] * chv[cap][1]
                    + chv[cap][2] * chv[cap][2] + chv[cap][3] * chv[cap][3];
            #pragma unroll
            for (int off = 1; off <= 8; off <<= 1) p += __shfl_xor(p, off);
            if (lane == 0) redp[cap][wp][wave] = p;
        }

        if (it < 2) {
            #pragma unroll
            for (int cap = 0; cap < CPB; ++cap) {
                #pragma unroll
                for (int i = 0; i < 4; ++i)
                    #pragma unroll
                    for (int r = 0; r < 4; ++r) {
                        float s = acc[cap][i * 4 + 0][r] * chv[cap][0] + acc[cap][i * 4 + 1][r] * chv[cap][1]
                                + acc[cap][i * 4 + 2][r] * chv[cap][2] + acc[cap][i * 4 + 3][r] * chv[cap][3];
                        #pragma unroll
                        for (int off = 1; off <= 8; off <<= 1) s += __shfl_xor(s, off);
                        if (l15 == 0) bpart[cap][wp][wave][i * 16 + l4 * 4 + r] = s;
                    }
            }
            __syncthreads();
        } else {
            #pragma unroll
            for (int cap = 0; cap < CPB; ++cap) {
                if (l4 == 0) {
                    #pragma unroll
                    for (int j = 0; j < 4; ++j)
                        chatL[cap][wave * 64 + j * 16 + l15] = chv[cap][j];
                }
            }
            __syncthreads();
            #pragma unroll
            for (int cap = 0; cap < CPB; ++cap) {
                float n2f = 0.f;
                #pragma unroll
                for (int w = 0; w < 8; ++w) n2f += redp[cap][wp][w];
                float alphaf = sqrtf(n2f) / (1.0f + n2f);
                out[(size_t)(c0 + cap) * HD + tid] = alphaf * chatL[cap][tid];
            }
        }
    }
}

extern "C" void kernel_launch(void* const* d_in, const int* in_sizes, int n_in,
                              void* d_out, int out_size, void* d_ws, size_t ws_size,
                              hipStream_t stream) {
    const float* enc = (const float*)d_in[0];   // [1024, 64, 512] fp32
    const float* W   = (const float*)d_in[1];   // [512, 512] fp32
    float* out       = (float*)d_out;           // [1024, 512] fp32
    _Float16* Wp     = (_Float16*)d_ws;         // 512 KB, B-fragment order
    (void)in_sizes; (void)n_in; (void)ws_size; (void)out_size;

    cast_w_kernel<<<128, 256, 0, stream>>>(W, Wp);
    routing_kernel<<<1024 / CPB, NT, 0, stream>>>(enc, Wp, out);
}